// Round 13
// baseline (140.065 us; speedup 1.0000x reference)
//
#include <hip/hip_runtime.h>
#include <hip/hip_bf16.h>
#include <math.h>

#define B_   8
#define N_   1024
#define FIN  128
#define FOUT 128
#define H_   8
#define NEG  0.2f
#define LOG2E 1.4426950408889634f

typedef __attribute__((ext_vector_type(4))) float f32x4;
typedef __attribute__((ext_vector_type(8))) short s16x8;

static __device__ __forceinline__ unsigned short f2bf(float f) {
    unsigned int u = __float_as_uint(f);
    unsigned int r = (u + 0x7fffu + ((u >> 16) & 1u)) >> 16;   // RNE (software)
    return (unsigned short)r;
}

static __device__ __forceinline__ unsigned short f2bf_hw(float f) {
    union { __hip_bfloat16 b; unsigned short u; } cv;
    cv.b = __float2bfloat16(f);
    return cv.u;
}

static __device__ __forceinline__ float bf2f(unsigned short u) {
    return __uint_as_float(((unsigned int)u) << 16);
}

// async global->LDS, 16B per lane, wave-uniform LDS base + lane*16
static __device__ __forceinline__ void gll16(const unsigned short* g, unsigned short* l) {
    __builtin_amdgcn_global_load_lds(
        (const __attribute__((address_space(1))) unsigned int*)g,
        (__attribute__((address_space(3))) unsigned int*)l, 16, 0, 0);
}

// ---------------- K0: biasm[i][j] = adj ? bf16(bias*log2e) : -inf(bf16) --------------
__global__ __launch_bounds__(256) void k_bias(const int* __restrict__ adj,
                                              const float* __restrict__ bias,
                                              unsigned short* __restrict__ biasm) {
    const int base = (blockIdx.x * 256 + threadIdx.x) * 4;
    int4   av = *(const int4*)&adj[base];
    float4 bv = *(const float4*)&bias[base];
    ushort4 r;
    r.x = av.x ? f2bf_hw(bv.x * LOG2E) : (unsigned short)0xFF80;
    r.y = av.y ? f2bf_hw(bv.y * LOG2E) : (unsigned short)0xFF80;
    r.z = av.z ? f2bf_hw(bv.z * LOG2E) : (unsigned short)0xFF80;
    r.w = av.w ? f2bf_hw(bv.w * LOG2E) : (unsigned short)0xFF80;
    *(ushort4*)&biasm[base] = r;
}

// ---------------- K0b: W [H][FIN][FOUT] f32  ->  WT [H][FOUT][FIN] bf16 --------------
__global__ __launch_bounds__(256) void k_wt(const float* __restrict__ W,
                                            unsigned short* __restrict__ WT) {
    const int hd = blockIdx.x;
    const int t  = threadIdx.x;
    const int fo  = t >> 1;
    const int fi0 = (t & 1) * 64;
    const float* src = W + (size_t)hd * FIN * FOUT;
    unsigned short* dst = WT + ((size_t)hd * FOUT + fo) * FIN + fi0;
#pragma unroll
    for (int c = 0; c < 8; ++c) {
        s16x8 v;
#pragma unroll
        for (int u = 0; u < 8; ++u)
            v[u] = (short)f2bf(src[(size_t)(fi0 + c * 8 + u) * FOUT + fo]);
        *(s16x8*)(dst + c * 8) = v;
    }
}

// ---------------- K1: h' via bf16 MFMA + transpose-to-bf16 + s1/s2 epilogue ----------
// (known-good R9 version)
#define PADK 132
union SmemK1 {
    struct {
        unsigned short A[64 * PADK];
        unsigned short Bm[128 * PADK];
    } s;
    float tr[64 * PADK];
};

__global__ __launch_bounds__(256, 3) void k_hprime(const float* __restrict__ hsrc,
                                                   const unsigned short* __restrict__ WT,
                                                   const float* __restrict__ a,
                                                   unsigned short* __restrict__ hpT,
                                                   float* __restrict__ s1,
                                                   float* __restrict__ s2T) {
    __shared__ SmemK1 sm;
    const int t    = threadIdx.x;
    const int lane = t & 63;
    const int wave = t >> 6;
    const int bn0  = blockIdx.x * 64;
    const int hd   = blockIdx.y;

    {
        const int r = t >> 2, k0 = (t & 3) * 32;
        const float* src = hsrc + (size_t)(bn0 + r) * FIN + k0;
        unsigned short* dst = &sm.s.A[r * PADK + k0];
#pragma unroll
        for (int c = 0; c < 4; ++c) {
            float4 x = *(const float4*)&src[c * 8];
            float4 y = *(const float4*)&src[c * 8 + 4];
            s16x8 v;
            v[0] = (short)f2bf_hw(x.x); v[1] = (short)f2bf_hw(x.y);
            v[2] = (short)f2bf_hw(x.z); v[3] = (short)f2bf_hw(x.w);
            v[4] = (short)f2bf_hw(y.x); v[5] = (short)f2bf_hw(y.y);
            v[6] = (short)f2bf_hw(y.z); v[7] = (short)f2bf_hw(y.w);
            *(s16x8*)(dst + c * 8) = v;
        }
    }
    {
        const int r = t >> 1, k0 = (t & 1) * 64;
        const unsigned short* src = WT + ((size_t)hd * FOUT + r) * FIN + k0;
        unsigned short* dst = &sm.s.Bm[r * PADK + k0];
#pragma unroll
        for (int c = 0; c < 8; ++c)
            *(s16x8*)(dst + c * 8) = *(const s16x8*)(src + c * 8);
    }
    __syncthreads();

    const int wr   = wave * 16;
    const int arow = wr + (lane & 15);
    const int koff = (lane >> 4) * 8;
    f32x4 acc[8];
#pragma unroll
    for (int fc = 0; fc < 8; ++fc) acc[fc] = (f32x4){0.f, 0.f, 0.f, 0.f};
#pragma unroll
    for (int kk = 0; kk < 4; ++kk) {
        s16x8 av = *(const s16x8*)&sm.s.A[arow * PADK + kk * 32 + koff];
#pragma unroll
        for (int fc = 0; fc < 8; ++fc) {
            s16x8 bv = *(const s16x8*)&sm.s.Bm[(fc * 16 + (lane & 15)) * PADK + kk * 32 + koff];
            acc[fc] = __builtin_amdgcn_mfma_f32_16x16x32_bf16(av, bv, acc[fc], 0, 0, 0);
        }
    }
    __syncthreads();

#pragma unroll
    for (int fc = 0; fc < 8; ++fc)
#pragma unroll
        for (int r = 0; r < 4; ++r)
            sm.tr[(wr + (lane >> 4) * 4 + r) * PADK + fc * 16 + (lane & 15)] = acc[fc][r];
    __syncthreads();

    {
        const int f   = t >> 1;
        const int seg = (t & 1) * 32;
        const int b   = bn0 >> 10;
        const int n0  = bn0 & 1023;
        unsigned short* dst = hpT + (((size_t)(b * H_ + hd) * FOUT + f) * N_) + n0 + seg;
#pragma unroll
        for (int c = 0; c < 4; ++c) {
            s16x8 v;
#pragma unroll
            for (int u = 0; u < 8; ++u)
                v[u] = (short)f2bf_hw(sm.tr[(seg + c * 8 + u) * PADK + f]);
            *(s16x8*)(dst + c * 8) = v;
        }
    }
    {
        const int row = t >> 2, f0 = (t & 3) * 32;
        const float* a1 = a + (size_t)hd * 2 * FOUT;
        const float* a2 = a1 + FOUT;
        float v1 = 0.f, v2 = 0.f;
#pragma unroll 8
        for (int fi = 0; fi < 32; ++fi) {
            float hv = sm.tr[row * PADK + f0 + fi];
            v1 += hv * a1[f0 + fi];
            v2 += hv * a2[f0 + fi];
        }
        v1 += __shfl_xor(v1, 1); v1 += __shfl_xor(v1, 2);
        v2 += __shfl_xor(v2, 1); v2 += __shfl_xor(v2, 2);
        if ((t & 3) == 0) {
            int bn = bn0 + row;
            s1[(size_t)bn * 8 + hd]          = v1 * LOG2E;   // pre-scale for exp2
            s2T[(size_t)hd * (B_ * N_) + bn] = v2 * LOG2E;
        }
    }
}

// ---------------- K2: producer/consumer wave-specialized P-gen + MFMA PV -------------
// grid (N/64, H, B) = 1024 blocks, 512 threads.
// Waves 0-3: producers (gll B-staging, bias/s2 loads, exp2 P-gen into LDS, Z).
// Waves 4-7: consumers (pure ds_read + MFMA, 32i x 64f tile each).
// One barrier per j-iter; P and B double-buffered so producer(it+1) || consumer(it).
#define LOADR(j0, b0, b1, s_) {                            \
    b0 = *(const s16x8*)&bm_row[(j0) + pj0];               \
    b1 = *(const s16x8*)&bm_row[(j0) + pj0 + 8];           \
    s_[0] = *(const float4*)&s2p[(j0) + pj0];              \
    s_[1] = *(const float4*)&s2p[(j0) + pj0 + 4];          \
    s_[2] = *(const float4*)&s2p[(j0) + pj0 + 8];          \
    s_[3] = *(const float4*)&s2p[(j0) + pj0 + 12];         \
}

__global__ __launch_bounds__(512, 4) void k_pv2(const unsigned short* __restrict__ hpT,
                                                const float* __restrict__ s1,
                                                const float* __restrict__ s2T,
                                                const unsigned short* __restrict__ biasm,
                                                float* __restrict__ out) {
    __shared__ __align__(16) unsigned short Pl[2][64 * 64];    // 16 KB, swizzled chunks
    __shared__ __align__(16) unsigned short Bl[2][128 * 64];   // 32 KB, swizzled chunks
    __shared__ float Zl[64];
    const int t    = threadIdx.x;
    const int lane = t & 63;
    const int wave = t >> 6;
    const bool producer = (wave < 4);
    const int i0 = blockIdx.x * 64;
    const int hd = blockIdx.y;
    const int b  = blockIdx.z;
    const unsigned short* hpS = hpT + (size_t)(b * H_ + hd) * FOUT * N_;

    // ---- producer state (threads 0..255): row = t>>2, 16 j per thread
    const int prow = (t >> 2) & 63;
    const int pj0  = (t & 3) * 16;
    const int pc0  = (t & 3) * 2;            // base 8-j chunk
    const int swzp = prow & 7;
    const float s1v = producer ? s1[(size_t)((b << 10) + i0 + prow) * 8 + hd] : 0.f;
    const unsigned short* bm_row = biasm + (size_t)(i0 + prow) * N_;
    const float* s2p = s2T + (size_t)hd * (B_ * N_) + (b << 10);
    float z_acc = 0.f;
    s16x8 bmv0A, bmv1A, bmv0B, bmv1B;
    float4 svA[4], svB[4];

    // ---- consumer state: wave tile 32i x 64f
    const int cw = wave & 3;
    const int wr = (cw & 1) * 32;
    const int wc = (cw >> 1) * 64;
    f32x4 acc[2][4];
#pragma unroll
    for (int i = 0; i < 2; ++i)
#pragma unroll
        for (int j = 0; j < 4; ++j) acc[i][j] = (f32x4){0.f, 0.f, 0.f, 0.f};

    // producers: 4 waves x 4 gll each stage the full 128f x 64j B tile (16 KB)
    auto stageB = [&](int j0, int buf) {
#pragma unroll
        for (int q = 0; q < 4; ++q) {
            const int c   = q * 256 + t;                 // t in 0..255 here
            const int row = c >> 3;
            const int col = c & 7;
            gll16(hpS + (size_t)row * N_ + j0 + ((col ^ (row & 7)) * 8),
                  &Bl[buf][(q * 256 + wave * 64) * 8]);  // wave-uniform base + lane*16
        }
    };

    auto pgenChunk = [&](int buf, int h, const s16x8& bmv,
                         const float4& q0, const float4& q1) {
        float x0 = s1v + q0.x; x0 = fmaxf(x0, NEG * x0) + bf2f((unsigned short)bmv[0]);
        float x1 = s1v + q0.y; x1 = fmaxf(x1, NEG * x1) + bf2f((unsigned short)bmv[1]);
        float x2 = s1v + q0.z; x2 = fmaxf(x2, NEG * x2) + bf2f((unsigned short)bmv[2]);
        float x3 = s1v + q0.w; x3 = fmaxf(x3, NEG * x3) + bf2f((unsigned short)bmv[3]);
        float x4 = s1v + q1.x; x4 = fmaxf(x4, NEG * x4) + bf2f((unsigned short)bmv[4]);
        float x5 = s1v + q1.y; x5 = fmaxf(x5, NEG * x5) + bf2f((unsigned short)bmv[5]);
        float x6 = s1v + q1.z; x6 = fmaxf(x6, NEG * x6) + bf2f((unsigned short)bmv[6]);
        float x7 = s1v + q1.w; x7 = fmaxf(x7, NEG * x7) + bf2f((unsigned short)bmv[7]);
        float p0 = exp2f(x0), p1 = exp2f(x1), p2 = exp2f(x2), p3 = exp2f(x3);
        float p4 = exp2f(x4), p5 = exp2f(x5), p6 = exp2f(x6), p7 = exp2f(x7);
        z_acc += ((p0 + p1) + (p2 + p3)) + ((p4 + p5) + (p6 + p7));
        s16x8 pv;
        pv[0] = (short)f2bf_hw(p0); pv[1] = (short)f2bf_hw(p1);
        pv[2] = (short)f2bf_hw(p2); pv[3] = (short)f2bf_hw(p3);
        pv[4] = (short)f2bf_hw(p4); pv[5] = (short)f2bf_hw(p5);
        pv[6] = (short)f2bf_hw(p6); pv[7] = (short)f2bf_hw(p7);
        *(s16x8*)&Pl[buf][prow * 64 + (((pc0 + h) ^ swzp) * 8)] = pv;
    };

    auto mf = [&](int buf) {
        __builtin_amdgcn_s_setprio(1);
#pragma unroll
        for (int kw = 0; kw < 2; ++kw) {
            const int achunk = kw * 4 + (lane >> 4);
            const int r0 = wr + (lane & 15);
            const int r1 = r0 + 16;
            s16x8 a0 = *(const s16x8*)&Pl[buf][r0 * 64 + ((achunk ^ (r0 & 7)) * 8)];
            s16x8 a1 = *(const s16x8*)&Pl[buf][r1 * 64 + ((achunk ^ (r1 & 7)) * 8)];
#pragma unroll
            for (int fc = 0; fc < 4; ++fc) {
                const int rb = wc + fc * 16 + (lane & 15);
                s16x8 bf = *(const s16x8*)&Bl[buf][rb * 64 + ((achunk ^ (rb & 7)) * 8)];
                acc[0][fc] = __builtin_amdgcn_mfma_f32_16x16x32_bf16(a0, bf, acc[0][fc], 0, 0, 0);
                acc[1][fc] = __builtin_amdgcn_mfma_f32_16x16x32_bf16(a1, bf, acc[1][fc], 0, 0, 0);
            }
        }
        __builtin_amdgcn_s_setprio(0);
    };

    // ---- prologue: producers build tile 0 (P and B), preload regs for tile 1
    if (producer) {
        LOADR(0, bmv0A, bmv1A, svA);
        stageB(0, 0);
        pgenChunk(0, 0, bmv0A, svA[0], svA[1]);
        pgenChunk(0, 1, bmv1A, svA[2], svA[3]);
        LOADR(64, bmv0A, bmv1A, svA);        // tile 1 -> set A
    }
    __syncthreads();

    // ---- steady state: one barrier per iter; producer(it+1) || consumer(it)
    for (int it = 0; it < 16; ++it) {
        const int cur = it & 1;
        if (producer) {
            if (it < 15) {
                stageB((it + 1) * 64, cur ^ 1);          // gll covered by pgen below
                if (it < 14) {                           // regs for tile it+2
                    if (cur == 0) LOADR((it + 2) * 64, bmv0B, bmv1B, svB)
                    else          LOADR((it + 2) * 64, bmv0A, bmv1A, svA)
                }
                if (cur == 0) {                          // set[cur] holds tile it+1
                    pgenChunk(cur ^ 1, 0, bmv0A, svA[0], svA[1]);
                    pgenChunk(cur ^ 1, 1, bmv1A, svA[2], svA[3]);
                } else {
                    pgenChunk(cur ^ 1, 0, bmv0B, svB[0], svB[1]);
                    pgenChunk(cur ^ 1, 1, bmv1B, svB[2], svB[3]);
                }
            }
        } else {
            mf(cur);
        }
        __syncthreads();
    }

    // ---- Z: 4 producer threads per row
    if (producer) {
        float z = z_acc;
        z += __shfl_xor(z, 1); z += __shfl_xor(z, 2);
        if ((t & 3) == 0) Zl[prow] = 0.125f / z;   // folds softmax norm + head-mean
    }
    __syncthreads();

    // ---- epilogue (consumers): C/D layout col=lane&15, row=(lane>>4)*4+reg
    if (!producer) {
#pragma unroll
        for (int rt = 0; rt < 2; ++rt) {
#pragma unroll
            for (int r = 0; r < 4; ++r) {
                const int il = wr + rt * 16 + (lane >> 4) * 4 + r;
                const float sc = Zl[il];
                float* op = out + ((size_t)((b << 10) + i0 + il)) * FOUT + wc + (lane & 15);
#pragma unroll
                for (int fc = 0; fc < 4; ++fc)
                    unsafeAtomicAdd(op + fc * 16, acc[rt][fc][r] * sc);
            }
        }
    }
}

extern "C" void kernel_launch(void* const* d_in, const int* in_sizes, int n_in,
                              void* d_out, int out_size, void* d_ws, size_t ws_size,
                              hipStream_t stream) {
    const float* hsrc = (const float*)d_in[0];
    const int*   adj  = (const int*)d_in[1];
    const float* bias = (const float*)d_in[2];
    const float* W    = (const float*)d_in[3];
    const float* a    = (const float*)d_in[4];
    float* out = (float*)d_out;

    char* ws = (char*)d_ws;
    unsigned short* hpT = (unsigned short*)ws;                     // 16 MB
    float* s1    = (float*)(ws + 16777216);                        // 256 KB
    float* s2T   = s1 + 65536;                                     // 256 KB
    unsigned short* biasm = (unsigned short*)(s2T + 65536);        // 2 MB (bf16)
    unsigned short* WT = biasm + (size_t)N_ * N_;                  // 256 KB

    hipMemsetAsync(d_out, 0, (size_t)out_size * sizeof(float), stream);
    k_bias<<<dim3(N_ * N_ / 1024), 256, 0, stream>>>(adj, bias, biasm);
    k_wt<<<dim3(H_), 256, 0, stream>>>(W, WT);
    k_hprime<<<dim3(B_ * N_ / 64, H_), 256, 0, stream>>>(hsrc, WT, a, hpT, s1, s2T);
    k_pv2<<<dim3(N_ / 64, H_, B_), 512, 0, stream>>>(hpT, s1, s2T, biasm, out);
}

// Round 14
// 100.656 us; speedup vs baseline: 1.3915x; 1.3915x over previous
//
#include <hip/hip_runtime.h>
#include <hip/hip_bf16.h>
#include <math.h>

#define B_   8
#define N_   1024
#define FIN  128
#define FOUT 128
#define H_   8
#define NEG  0.2f
#define LOG2E 1.4426950408889634f

typedef __attribute__((ext_vector_type(4))) float f32x4;
typedef __attribute__((ext_vector_type(8))) short s16x8;

static __device__ __forceinline__ unsigned short f2bf(float f) {
    unsigned int u = __float_as_uint(f);
    unsigned int r = (u + 0x7fffu + ((u >> 16) & 1u)) >> 16;   // RNE (software)
    return (unsigned short)r;
}

static __device__ __forceinline__ unsigned short f2bf_hw(float f) {
    union { __hip_bfloat16 b; unsigned short u; } cv;
    cv.b = __float2bfloat16(f);
    return cv.u;
}

// ---------------- K0: biasm[i][j] = adj ? bias*log2e : -inf (f32) --------------------
__global__ __launch_bounds__(256) void k_bias(const int* __restrict__ adj,
                                              const float* __restrict__ bias,
                                              float* __restrict__ biasm) {
    const int base = (blockIdx.x * 256 + threadIdx.x) * 4;
    int4   av = *(const int4*)&adj[base];
    float4 bv = *(const float4*)&bias[base];
    const float NINF = -__builtin_inff();
    float4 r;
    r.x = av.x ? bv.x * LOG2E : NINF;
    r.y = av.y ? bv.y * LOG2E : NINF;
    r.z = av.z ? bv.z * LOG2E : NINF;
    r.w = av.w ? bv.w * LOG2E : NINF;
    *(float4*)&biasm[base] = r;
}

// ---------------- K0b: W [H][FIN][FOUT] f32  ->  WT [H][FOUT][FIN] bf16 --------------
__global__ __launch_bounds__(256) void k_wt(const float* __restrict__ W,
                                            unsigned short* __restrict__ WT) {
    const int hd = blockIdx.x;
    const int t  = threadIdx.x;
    const int fo  = t >> 1;
    const int fi0 = (t & 1) * 64;
    const float* src = W + (size_t)hd * FIN * FOUT;
    unsigned short* dst = WT + ((size_t)hd * FOUT + fo) * FIN + fi0;
#pragma unroll
    for (int c = 0; c < 8; ++c) {
        s16x8 v;
#pragma unroll
        for (int u = 0; u < 8; ++u)
            v[u] = (short)f2bf(src[(size_t)(fi0 + c * 8 + u) * FOUT + fo]);
        *(s16x8*)(dst + c * 8) = v;
    }
}

// ---------------- K0c: wa[h][which][k] = log2e * sum_f W[h][k][f] * a[h][which][f] ---
// grid H, block 256 (which = t>>7, k = t&127)
__global__ __launch_bounds__(256) void k_wa(const float* __restrict__ W,
                                            const float* __restrict__ a,
                                            float* __restrict__ wa) {
    const int hd = blockIdx.x;
    const int t  = threadIdx.x;
    const int which = t >> 7, k = t & 127;
    const float* wrow = W + ((size_t)hd * FIN + k) * FOUT;
    const float* av   = a + (size_t)hd * 2 * FOUT + which * FOUT;
    float s = 0.f;
#pragma unroll 8
    for (int f = 0; f < FOUT; f += 4) {
        float4 wv = *(const float4*)&wrow[f];
        float4 a4 = *(const float4*)&av[f];
        s += wv.x * a4.x + wv.y * a4.y + wv.z * a4.z + wv.w * a4.w;
    }
    wa[((size_t)hd * 2 + which) * FIN + k] = s * LOG2E;
}

// ---------------- K0d: s1[bn][h], s2T[h][bn] = h . wa  (exact f32, pre-scaled) -------
// grid BN/16, block 256: 16 rows/block, 16 (h,which) dots per row
__global__ __launch_bounds__(256) void k_s12(const float* __restrict__ hsrc,
                                             const float* __restrict__ wa,
                                             float* __restrict__ s1,
                                             float* __restrict__ s2T) {
    __shared__ float hrow[16][132];
    __shared__ float wal[16][132];
    const int t   = threadIdx.x;
    const int bn0 = blockIdx.x * 16;
    {
        const int r = t >> 4, c = (t & 15) * 8;
        *(float4*)&wal[r][c]     = *(const float4*)&wa[r * FIN + c];
        *(float4*)&wal[r][c + 4] = *(const float4*)&wa[r * FIN + c + 4];
        *(float4*)&hrow[r][c]     = *(const float4*)&hsrc[(size_t)(bn0 + r) * FIN + c];
        *(float4*)&hrow[r][c + 4] = *(const float4*)&hsrc[(size_t)(bn0 + r) * FIN + c + 4];
    }
    __syncthreads();
    const int r = t >> 4, sub = t & 15;
    const int hd = sub >> 1, which = sub & 1;
    float s = 0.f;
#pragma unroll 8
    for (int k = 0; k < FIN; k += 4) {
        float4 hv = *(const float4*)&hrow[r][k];
        float4 wv = *(const float4*)&wal[sub][k];
        s += hv.x * wv.x + hv.y * wv.y + hv.z * wv.z + hv.w * wv.w;
    }
    const int bn = bn0 + r;
    if (which == 0) s1[(size_t)bn * 8 + hd] = s;
    else            s2T[(size_t)hd * (B_ * N_) + bn] = s;
}

// ---------------- K1: h' via bf16 MFMA + transpose-to-bf16 (no s1/s2) ----------------
#define PADK 132
union SmemK1 {
    struct {
        unsigned short A[64 * PADK];
        unsigned short Bm[128 * PADK];
    } s;
    float tr[64 * PADK];
};

__global__ __launch_bounds__(256, 3) void k_hprime(const float* __restrict__ hsrc,
                                                   const unsigned short* __restrict__ WT,
                                                   unsigned short* __restrict__ hpT) {
    __shared__ SmemK1 sm;
    const int t    = threadIdx.x;
    const int lane = t & 63;
    const int wave = t >> 6;
    const int bn0  = blockIdx.x * 64;
    const int hd   = blockIdx.y;

    {
        const int r = t >> 2, k0 = (t & 3) * 32;
        const float* src = hsrc + (size_t)(bn0 + r) * FIN + k0;
        unsigned short* dst = &sm.s.A[r * PADK + k0];
#pragma unroll
        for (int c = 0; c < 4; ++c) {
            float4 x = *(const float4*)&src[c * 8];
            float4 y = *(const float4*)&src[c * 8 + 4];
            s16x8 v;
            v[0] = (short)f2bf_hw(x.x); v[1] = (short)f2bf_hw(x.y);
            v[2] = (short)f2bf_hw(x.z); v[3] = (short)f2bf_hw(x.w);
            v[4] = (short)f2bf_hw(y.x); v[5] = (short)f2bf_hw(y.y);
            v[6] = (short)f2bf_hw(y.z); v[7] = (short)f2bf_hw(y.w);
            *(s16x8*)(dst + c * 8) = v;
        }
    }
    {
        const int r = t >> 1, k0 = (t & 1) * 64;
        const unsigned short* src = WT + ((size_t)hd * FOUT + r) * FIN + k0;
        unsigned short* dst = &sm.s.Bm[r * PADK + k0];
#pragma unroll
        for (int c = 0; c < 8; ++c)
            *(s16x8*)(dst + c * 8) = *(const s16x8*)(src + c * 8);
    }
    __syncthreads();

    const int wr   = wave * 16;
    const int arow = wr + (lane & 15);
    const int koff = (lane >> 4) * 8;
    f32x4 acc[8];
#pragma unroll
    for (int fc = 0; fc < 8; ++fc) acc[fc] = (f32x4){0.f, 0.f, 0.f, 0.f};
#pragma unroll
    for (int kk = 0; kk < 4; ++kk) {
        s16x8 av = *(const s16x8*)&sm.s.A[arow * PADK + kk * 32 + koff];
#pragma unroll
        for (int fc = 0; fc < 8; ++fc) {
            s16x8 bv = *(const s16x8*)&sm.s.Bm[(fc * 16 + (lane & 15)) * PADK + kk * 32 + koff];
            acc[fc] = __builtin_amdgcn_mfma_f32_16x16x32_bf16(av, bv, acc[fc], 0, 0, 0);
        }
    }
    __syncthreads();

#pragma unroll
    for (int fc = 0; fc < 8; ++fc)
#pragma unroll
        for (int r = 0; r < 4; ++r)
            sm.tr[(wr + (lane >> 4) * 4 + r) * PADK + fc * 16 + (lane & 15)] = acc[fc][r];
    __syncthreads();

    {
        const int f   = t >> 1;
        const int seg = (t & 1) * 32;
        const int b   = bn0 >> 10;
        const int n0  = bn0 & 1023;
        unsigned short* dst = hpT + (((size_t)(b * H_ + hd) * FOUT + f) * N_) + n0 + seg;
#pragma unroll
        for (int c = 0; c < 4; ++c) {
            s16x8 v;
#pragma unroll
            for (int u = 0; u < 8; ++u)
                v[u] = (short)f2bf_hw(sm.tr[(seg + c * 8 + u) * PADK + f]);
            *(s16x8*)(dst + c * 8) = v;
        }
    }
}

// ---------------- K2: fused P-gen + MFMA PV (best-known 59us structure, exp2) --------
// grid (N/32, H, B), block 256 (4 waves, each 16 rows x 64 cols)
__global__ __launch_bounds__(256, 8) void k_pv2(const unsigned short* __restrict__ hpT,
                                                const float* __restrict__ s1,
                                                const float* __restrict__ s2T,
                                                const float* __restrict__ biasm,
                                                float* __restrict__ out) {
    __shared__ __align__(16) unsigned short P[32][72];    // 4.6 KB
    __shared__ __align__(16) unsigned short Bl[128 * 64]; // 16 KB, XOR-swizzled chunks
    __shared__ float Zl[32];
    const int t    = threadIdx.x;
    const int lane = t & 63;
    const int wave = t >> 6;
    const int i0 = blockIdx.x * 32;
    const int hd = blockIdx.y;
    const int b  = blockIdx.z;

    // P-gen assignment: one row per 8 threads, 8 consecutive j each
    const int prow = t >> 3;          // 0..31
    const int pj0  = (t & 7) * 8;     // 0..56
    const int gi   = (b << 10) + i0 + prow;
    const float s1v = s1[(size_t)gi * 8 + hd];
    const float* bm_row = biasm + (size_t)(i0 + prow) * N_;
    const float* s2p    = s2T + (size_t)hd * (B_ * N_) + (b << 10);

    // B staging: thread t covers chunk ids {q*256+t}, id -> (f-row id>>3, chunk id&7)
    const unsigned short* hpS = hpT + (size_t)(b * H_ + hd) * FOUT * N_;
    const int brow = t >> 3;          // base f-row for q=0 (rows 0..31)
    const int bc   = t & 7;           // 16B chunk within 128B j-row

    // wave output tile: 16 rows x 64 cols
    const int wr = (wave & 1) * 16;
    const int wc = (wave >> 1) * 64;
    const int arow = wr + (lane & 15);
    const int koff = (lane >> 4) * 8;

    f32x4 acc[4];
#pragma unroll
    for (int j = 0; j < 4; ++j) acc[j] = (f32x4){0.f, 0.f, 0.f, 0.f};
    float z_acc = 0.f;

    float4 bmv[2], sv[2];
    s16x8 Breg[4];

    auto load_it = [&](int j0) {
#pragma unroll
        for (int q = 0; q < 2; ++q) {
            bmv[q] = *(const float4*)&bm_row[j0 + pj0 + q * 4];
            sv[q]  = *(const float4*)&s2p[j0 + pj0 + q * 4];
        }
    };
    auto bload = [&](int j0) {
#pragma unroll
        for (int q = 0; q < 4; ++q)
            Breg[q] = *(const s16x8*)&hpS[(size_t)(brow + q * 32) * N_ + j0 + bc * 8];
    };
    auto phaseA = [&]() {
        // swizzled LDS write of B tile
#pragma unroll
        for (int q = 0; q < 4; ++q) {
            int row = brow + q * 32;
            *(s16x8*)&Bl[row * 64 + ((bc ^ (row & 7)) * 8)] = Breg[q];
        }
        // P-gen + Z: 8 scores -> one 16B LDS write (all inputs pre-scaled by log2e)
        s16x8 pv;
#pragma unroll
        for (int q = 0; q < 2; ++q) {
            float x0 = s1v + sv[q].x; x0 = fmaxf(x0, NEG * x0) + bmv[q].x;
            float x1 = s1v + sv[q].y; x1 = fmaxf(x1, NEG * x1) + bmv[q].y;
            float x2 = s1v + sv[q].z; x2 = fmaxf(x2, NEG * x2) + bmv[q].z;
            float x3 = s1v + sv[q].w; x3 = fmaxf(x3, NEG * x3) + bmv[q].w;
            float p0 = exp2f(x0);   // exp2(-inf) = 0 handles the adj mask
            float p1 = exp2f(x1);
            float p2 = exp2f(x2);
            float p3 = exp2f(x3);
            z_acc += (p0 + p1) + (p2 + p3);
            pv[q * 4 + 0] = (short)f2bf_hw(p0);
            pv[q * 4 + 1] = (short)f2bf_hw(p1);
            pv[q * 4 + 2] = (short)f2bf_hw(p2);
            pv[q * 4 + 3] = (short)f2bf_hw(p3);
        }
        *(s16x8*)&P[prow][pj0] = pv;
    };

    // prologue
    bload(0);
    load_it(0);

    for (int it = 0; it < 16; ++it) {
        const int j0 = it * 64;
        phaseA();                       // LDS writes of B + P (consumes regs)
        __syncthreads();
        if (it < 15) { bload(j0 + 64); load_it(j0 + 64); }   // overlap with MFMA below
        // ---- MFMA phase: A (P) and B (h') fragments from LDS
#pragma unroll
        for (int kw = 0; kw < 2; ++kw) {
            s16x8 a0 = *(const s16x8*)&P[arow][kw * 32 + koff];
#pragma unroll
            for (int fc = 0; fc < 4; ++fc) {
                const int r = wc + fc * 16 + (lane & 15);
                const int chunk = (lane >> 4) + kw * 4;
                s16x8 bf = *(const s16x8*)&Bl[r * 64 + ((chunk ^ (r & 7)) * 8)];
                acc[fc] = __builtin_amdgcn_mfma_f32_16x16x32_bf16(a0, bf, acc[fc], 0, 0, 0);
            }
        }
        __syncthreads();
    }

    // Z: reduce 8 lanes per row (lanes grouped consecutively)
    float z = z_acc;
    z += __shfl_xor(z, 1); z += __shfl_xor(z, 2); z += __shfl_xor(z, 4);
    if ((t & 7) == 0) Zl[prow] = 0.125f / z;   // folds softmax norm + head-mean
    __syncthreads();

    // epilogue: C/D layout col=lane&15, row=(lane>>4)*4+reg
#pragma unroll
    for (int r = 0; r < 4; ++r) {
        const int il = wr + (lane >> 4) * 4 + r;
        const float sc = Zl[il];
        float* op = out + ((size_t)((b << 10) + i0 + il)) * FOUT + wc + (lane & 15);
#pragma unroll
        for (int fc = 0; fc < 4; ++fc)
            unsafeAtomicAdd(op + fc * 16, acc[fc][r] * sc);
    }
}

extern "C" void kernel_launch(void* const* d_in, const int* in_sizes, int n_in,
                              void* d_out, int out_size, void* d_ws, size_t ws_size,
                              hipStream_t stream) {
    const float* hsrc = (const float*)d_in[0];
    const int*   adj  = (const int*)d_in[1];
    const float* bias = (const float*)d_in[2];
    const float* W    = (const float*)d_in[3];
    const float* a    = (const float*)d_in[4];
    float* out = (float*)d_out;

    char* ws = (char*)d_ws;
    unsigned short* hpT = (unsigned short*)ws;                 // 16 MB
    float* s1    = (float*)(ws + 16777216);                    // 256 KB
    float* s2T   = s1 + 65536;                                 // 256 KB
    float* biasm = s2T + 65536;                                // 4 MB (f32, log2e-scaled)
    unsigned short* WT = (unsigned short*)(biasm + N_ * N_);   // 256 KB
    float* wa = (float*)(WT + (size_t)H_ * FOUT * FIN);        // 8 KB

    hipMemsetAsync(d_out, 0, (size_t)out_size * sizeof(float), stream);
    k_bias<<<dim3(N_ * N_ / 1024), 256, 0, stream>>>(adj, bias, biasm);
    k_wt<<<dim3(H_), 256, 0, stream>>>(W, WT);
    k_wa<<<dim3(H_), 256, 0, stream>>>(W, a, wa);
    k_s12<<<dim3(B_ * N_ / 16), 256, 0, stream>>>(hsrc, wa, s1, s2T);
    k_hprime<<<dim3(B_ * N_ / 64, H_), 256, 0, stream>>>(hsrc, WT, hpT);
    k_pv2<<<dim3(N_ / 32, H_, B_), 256, 0, stream>>>(hpT, s1, s2T, biasm, out);
}

// Round 15
// 88.992 us; speedup vs baseline: 1.5739x; 1.1311x over previous
//
#include <hip/hip_runtime.h>
#include <hip/hip_bf16.h>
#include <math.h>

#define B_   8
#define N_   1024
#define FIN  128
#define FOUT 128
#define H_   8
#define NEG  0.2f
#define LOG2E 1.4426950408889634f

typedef __attribute__((ext_vector_type(4))) float f32x4;
typedef __attribute__((ext_vector_type(8))) short s16x8;

static __device__ __forceinline__ unsigned short f2bf(float f) {
    unsigned int u = __float_as_uint(f);
    unsigned int r = (u + 0x7fffu + ((u >> 16) & 1u)) >> 16;   // RNE (software)
    return (unsigned short)r;
}

static __device__ __forceinline__ unsigned short f2bf_hw(float f) {
    union { __hip_bfloat16 b; unsigned short u; } cv;
    cv.b = __float2bfloat16(f);
    return cv.u;
}

// ---------------- K0: biasm[i][j] = adj ? bias*log2e : -inf (f32) --------------------
__global__ __launch_bounds__(256) void k_bias(const int* __restrict__ adj,
                                              const float* __restrict__ bias,
                                              float* __restrict__ biasm) {
    const int base = (blockIdx.x * 256 + threadIdx.x) * 4;
    int4   av = *(const int4*)&adj[base];
    float4 bv = *(const float4*)&bias[base];
    const float NINF = -__builtin_inff();
    float4 r;
    r.x = av.x ? bv.x * LOG2E : NINF;
    r.y = av.y ? bv.y * LOG2E : NINF;
    r.z = av.z ? bv.z * LOG2E : NINF;
    r.w = av.w ? bv.w * LOG2E : NINF;
    *(float4*)&biasm[base] = r;
}

// ---------------- K0b: W [H][FIN][FOUT] f32  ->  WT [H][FOUT][FIN] bf16 --------------
__global__ __launch_bounds__(256) void k_wt(const float* __restrict__ W,
                                            unsigned short* __restrict__ WT) {
    const int hd = blockIdx.x;
    const int t  = threadIdx.x;
    const int fo  = t >> 1;
    const int fi0 = (t & 1) * 64;
    const float* src = W + (size_t)hd * FIN * FOUT;
    unsigned short* dst = WT + ((size_t)hd * FOUT + fo) * FIN + fi0;
#pragma unroll
    for (int c = 0; c < 8; ++c) {
        s16x8 v;
#pragma unroll
        for (int u = 0; u < 8; ++u)
            v[u] = (short)f2bf(src[(size_t)(fi0 + c * 8 + u) * FOUT + fo]);
        *(s16x8*)(dst + c * 8) = v;
    }
}

// ---------------- K0c: wa[h][which][k] = log2e * sum_f W[h][k][f] * a[h][which][f] ---
__global__ __launch_bounds__(256) void k_wa(const float* __restrict__ W,
                                            const float* __restrict__ a,
                                            float* __restrict__ wa) {
    const int hd = blockIdx.x;
    const int t  = threadIdx.x;
    const int which = t >> 7, k = t & 127;
    const float* wrow = W + ((size_t)hd * FIN + k) * FOUT;
    const float* av   = a + (size_t)hd * 2 * FOUT + which * FOUT;
    float s = 0.f;
#pragma unroll 8
    for (int f = 0; f < FOUT; f += 4) {
        float4 wv = *(const float4*)&wrow[f];
        float4 a4 = *(const float4*)&av[f];
        s += wv.x * a4.x + wv.y * a4.y + wv.z * a4.z + wv.w * a4.w;
    }
    wa[((size_t)hd * 2 + which) * FIN + k] = s * LOG2E;
}

// ---------------- K0d: s1[bn][h], s2T[h][bn] = h . wa  (exact f32, pre-scaled) -------
__global__ __launch_bounds__(256) void k_s12(const float* __restrict__ hsrc,
                                             const float* __restrict__ wa,
                                             float* __restrict__ s1,
                                             float* __restrict__ s2T) {
    __shared__ float hrow[16][132];
    __shared__ float wal[16][132];
    const int t   = threadIdx.x;
    const int bn0 = blockIdx.x * 16;
    {
        const int r = t >> 4, c = (t & 15) * 8;
        *(float4*)&wal[r][c]     = *(const float4*)&wa[r * FIN + c];
        *(float4*)&wal[r][c + 4] = *(const float4*)&wa[r * FIN + c + 4];
        *(float4*)&hrow[r][c]     = *(const float4*)&hsrc[(size_t)(bn0 + r) * FIN + c];
        *(float4*)&hrow[r][c + 4] = *(const float4*)&hsrc[(size_t)(bn0 + r) * FIN + c + 4];
    }
    __syncthreads();
    const int r = t >> 4, sub = t & 15;
    const int hd = sub >> 1, which = sub & 1;
    float s = 0.f;
#pragma unroll 8
    for (int k = 0; k < FIN; k += 4) {
        float4 hv = *(const float4*)&hrow[r][k];
        float4 wv = *(const float4*)&wal[sub][k];
        s += hv.x * wv.x + hv.y * wv.y + hv.z * wv.z + hv.w * wv.w;
    }
    const int bn = bn0 + r;
    if (which == 0) s1[(size_t)bn * 8 + hd] = s;
    else            s2T[(size_t)hd * (B_ * N_) + bn] = s;
}

// ---------------- K0e: h [B][N][FIN] f32 -> hbT [B][FIN][N] bf16 ---------------------
// grid B*N/64 = 128, block 256
__global__ __launch_bounds__(256) void k_ht(const float* __restrict__ hsrc,
                                            unsigned short* __restrict__ hbT) {
    __shared__ float tf[64][132];
    const int t   = threadIdx.x;
    const int bn0 = blockIdx.x * 64;
    const int b   = bn0 >> 10;
    const int n0  = bn0 & 1023;
    {
        const int r = t >> 2, k0 = (t & 3) * 32;
        const float* src = hsrc + (size_t)(bn0 + r) * FIN + k0;
#pragma unroll
        for (int c = 0; c < 8; ++c)
            *(float4*)&tf[r][k0 + c * 4] = *(const float4*)&src[c * 4];
    }
    __syncthreads();
    {
        const int k   = t >> 1;
        const int seg = (t & 1) * 32;
        unsigned short* dst = hbT + ((size_t)b * FIN + k) * N_ + n0 + seg;
#pragma unroll
        for (int c = 0; c < 4; ++c) {
            s16x8 v;
#pragma unroll
            for (int u = 0; u < 8; ++u)
                v[u] = (short)f2bf_hw(tf[seg + c * 8 + u][k]);
            *(s16x8*)(dst + c * 8) = v;
        }
    }
}

// ---------------- K2: fused P-gen + MFMA (P.h) + fused G@W epilogue ------------------
// 1D grid 2048, XCD-swizzled: batch b pins to one XCD (hbT slice 256KB L2-resident).
// Main loop = proven 59us structure; B-source = hbT (shared across heads).
__global__ __launch_bounds__(256, 5) void k_pv2(const unsigned short* __restrict__ hbT,
                                                const float* __restrict__ s1,
                                                const float* __restrict__ s2T,
                                                const float* __restrict__ biasm,
                                                const unsigned short* __restrict__ WT,
                                                float* __restrict__ out) {
    __shared__ __align__(16) unsigned short P[32][72];     // 4.5 KB
    __shared__ __align__(16) unsigned short Bl[128 * 64];  // 16 KB, XOR-swizzled chunks
    __shared__ __align__(16) unsigned short Gl[32][136];   // 8.5 KB, padded
    __shared__ float Zl[32];
    const int t    = threadIdx.x;
    const int lane = t & 63;
    const int wave = t >> 6;
    // bijective XCD swizzle (2048 % 8 == 0): XCD k gets all blocks of batch k
    const int wg  = blockIdx.x;
    const int swz = ((wg & 7) << 8) | (wg >> 3);
    const int i0  = (swz & 31) * 32;
    const int hd  = (swz >> 5) & 7;
    const int b   = swz >> 8;

    // P-gen assignment: one row per 8 threads, 8 consecutive j each
    const int prow = t >> 3;          // 0..31
    const int pj0  = (t & 7) * 8;     // 0..56
    const int gi   = (b << 10) + i0 + prow;
    const float s1v = s1[(size_t)gi * 8 + hd];
    const float* bm_row = biasm + (size_t)(i0 + prow) * N_;
    const float* s2p    = s2T + (size_t)hd * (B_ * N_) + (b << 10);

    // B staging source: hbT batch slice (k-rows of N)
    const unsigned short* hpS = hbT + (size_t)b * FIN * N_;
    const int brow = t >> 3;          // base k-row for q=0 (rows 0..31)
    const int bc   = t & 7;           // 16B chunk within 128B j-row

    // wave tile (main loop): 16 i-rows x 64 k-cols
    const int wr = (wave & 1) * 16;
    const int wc = (wave >> 1) * 64;
    const int arow = wr + (lane & 15);
    const int koff = (lane >> 4) * 8;

    f32x4 acc[4];
#pragma unroll
    for (int j = 0; j < 4; ++j) acc[j] = (f32x4){0.f, 0.f, 0.f, 0.f};
    float z_acc = 0.f;

    float4 bmv[2], sv[2];
    s16x8 Breg[4];

    auto load_it = [&](int j0) {
#pragma unroll
        for (int q = 0; q < 2; ++q) {
            bmv[q] = *(const float4*)&bm_row[j0 + pj0 + q * 4];
            sv[q]  = *(const float4*)&s2p[j0 + pj0 + q * 4];
        }
    };
    auto bload = [&](int j0) {
#pragma unroll
        for (int q = 0; q < 4; ++q)
            Breg[q] = *(const s16x8*)&hpS[(size_t)(brow + q * 32) * N_ + j0 + bc * 8];
    };
    auto phaseA = [&]() {
#pragma unroll
        for (int q = 0; q < 4; ++q) {
            int row = brow + q * 32;
            *(s16x8*)&Bl[row * 64 + ((bc ^ (row & 7)) * 8)] = Breg[q];
        }
        s16x8 pv;
#pragma unroll
        for (int q = 0; q < 2; ++q) {
            float x0 = s1v + sv[q].x; x0 = fmaxf(x0, NEG * x0) + bmv[q].x;
            float x1 = s1v + sv[q].y; x1 = fmaxf(x1, NEG * x1) + bmv[q].y;
            float x2 = s1v + sv[q].z; x2 = fmaxf(x2, NEG * x2) + bmv[q].z;
            float x3 = s1v + sv[q].w; x3 = fmaxf(x3, NEG * x3) + bmv[q].w;
            float p0 = exp2f(x0);   // exp2(-inf) = 0 handles the adj mask
            float p1 = exp2f(x1);
            float p2 = exp2f(x2);
            float p3 = exp2f(x3);
            z_acc += (p0 + p1) + (p2 + p3);
            pv[q * 4 + 0] = (short)f2bf_hw(p0);
            pv[q * 4 + 1] = (short)f2bf_hw(p1);
            pv[q * 4 + 2] = (short)f2bf_hw(p2);
            pv[q * 4 + 3] = (short)f2bf_hw(p3);
        }
        *(s16x8*)&P[prow][pj0] = pv;
    };

    // ---- main loop: G_tile = P . h  (identical structure to proven 59us kernel)
    bload(0);
    load_it(0);
    for (int it = 0; it < 16; ++it) {
        const int j0 = it * 64;
        phaseA();
        __syncthreads();
        if (it < 15) { bload(j0 + 64); load_it(j0 + 64); }
#pragma unroll
        for (int kw = 0; kw < 2; ++kw) {
            s16x8 a0 = *(const s16x8*)&P[arow][kw * 32 + koff];
#pragma unroll
            for (int fc = 0; fc < 4; ++fc) {
                const int r = wc + fc * 16 + (lane & 15);
                const int chunk = (lane >> 4) + kw * 4;
                s16x8 bf = *(const s16x8*)&Bl[r * 64 + ((chunk ^ (r & 7)) * 8)];
                acc[fc] = __builtin_amdgcn_mfma_f32_16x16x32_bf16(a0, bf, acc[fc], 0, 0, 0);
            }
        }
        __syncthreads();
    }

    // ---- Z: reduce 8 lanes per row
    float z = z_acc;
    z += __shfl_xor(z, 1); z += __shfl_xor(z, 2); z += __shfl_xor(z, 4);
    if ((t & 7) == 0) Zl[prow] = 0.125f / z;   // folds softmax norm + head-mean

    // issue W half-0 loads (k 0..63), covered by Gl writes below
    const unsigned short* Wsrc = WT + (size_t)hd * FOUT * FIN;
    s16x8 Wreg[4];
#pragma unroll
    for (int q = 0; q < 4; ++q)
        Wreg[q] = *(const s16x8*)&Wsrc[(size_t)(brow + q * 32) * FIN + bc * 8];
    __syncthreads();   // Zl visible; Bl free (all waves past last MFMA)

    // ---- write scaled G tile (bf16) into Gl; C/D layout col=lane&15, row=(lane>>4)*4+r
#pragma unroll
    for (int r = 0; r < 4; ++r) {
        const int il = wr + (lane >> 4) * 4 + r;
        const float sc = Zl[il];
#pragma unroll
        for (int fc = 0; fc < 4; ++fc)
            Gl[il][wc + fc * 16 + (lane & 15)] = f2bf_hw(acc[fc][r] * sc);
    }
    // swizzled ds_write W half-0 into Bl (same involution as main loop)
#pragma unroll
    for (int q = 0; q < 4; ++q) {
        int row = brow + q * 32;
        *(s16x8*)&Bl[row * 64 + ((bc ^ (row & 7)) * 8)] = Wreg[q];
    }
    // issue W half-1 loads (k 64..127)
#pragma unroll
    for (int q = 0; q < 4; ++q)
        Wreg[q] = *(const s16x8*)&Wsrc[(size_t)(brow + q * 32) * FIN + 64 + bc * 8];
    __syncthreads();   // Gl + W-half0 visible

    // ---- out_tile = G @ W[hd]; wave tile: 16i x 64f
    const int wr2 = (wave & 1) * 16;
    const int wc2 = (wave >> 1) * 64;
    f32x4 acc2[4];
#pragma unroll
    for (int j = 0; j < 4; ++j) acc2[j] = (f32x4){0.f, 0.f, 0.f, 0.f};

#pragma unroll
    for (int kw = 0; kw < 2; ++kw) {                 // k 0..63
        s16x8 a0 = *(const s16x8*)&Gl[wr2 + (lane & 15)][kw * 32 + koff];
#pragma unroll
        for (int fc = 0; fc < 4; ++fc) {
            const int rb = wc2 + fc * 16 + (lane & 15);
            const int chunk = (lane >> 4) + kw * 4;
            s16x8 bf = *(const s16x8*)&Bl[rb * 64 + ((chunk ^ (rb & 7)) * 8)];
            acc2[fc] = __builtin_amdgcn_mfma_f32_16x16x32_bf16(a0, bf, acc2[fc], 0, 0, 0);
        }
    }
    __syncthreads();   // done reading W-half0
#pragma unroll
    for (int q = 0; q < 4; ++q) {                    // W half-1 into Bl
        int row = brow + q * 32;
        *(s16x8*)&Bl[row * 64 + ((bc ^ (row & 7)) * 8)] = Wreg[q];
    }
    __syncthreads();
#pragma unroll
    for (int kw = 0; kw < 2; ++kw) {                 // k 64..127
        s16x8 a0 = *(const s16x8*)&Gl[wr2 + (lane & 15)][64 + kw * 32 + koff];
#pragma unroll
        for (int fc = 0; fc < 4; ++fc) {
            const int rb = wc2 + fc * 16 + (lane & 15);
            const int chunk = (lane >> 4) + kw * 4;
            s16x8 bf = *(const s16x8*)&Bl[rb * 64 + ((chunk ^ (rb & 7)) * 8)];
            acc2[fc] = __builtin_amdgcn_mfma_f32_16x16x32_bf16(a0, bf, acc2[fc], 0, 0, 0);
        }
    }

    // ---- accumulate over heads: C/D layout col=lane&15, row=(lane>>4)*4+r
#pragma unroll
    for (int r = 0; r < 4; ++r) {
        const int il = wr2 + (lane >> 4) * 4 + r;
        float* op = out + ((size_t)((b << 10) + i0 + il)) * FOUT + wc2 + (lane & 15);
#pragma unroll
        for (int fc = 0; fc < 4; ++fc)
            unsafeAtomicAdd(op + fc * 16, acc2[fc][r]);
    }
}

extern "C" void kernel_launch(void* const* d_in, const int* in_sizes, int n_in,
                              void* d_out, int out_size, void* d_ws, size_t ws_size,
                              hipStream_t stream) {
    const float* hsrc = (const float*)d_in[0];
    const int*   adj  = (const int*)d_in[1];
    const float* bias = (const float*)d_in[2];
    const float* W    = (const float*)d_in[3];
    const float* a    = (const float*)d_in[4];
    float* out = (float*)d_out;

    char* ws = (char*)d_ws;
    unsigned short* hbT = (unsigned short*)ws;                 // 2 MB (bf16 h^T per batch)
    float* s1    = (float*)(ws + 2097152);                     // 256 KB
    float* s2T   = s1 + 65536;                                 // 256 KB
    float* biasm = s2T + 65536;                                // 4 MB (f32, log2e-scaled)
    unsigned short* WT = (unsigned short*)(biasm + N_ * N_);   // 256 KB
    float* wa = (float*)(WT + (size_t)H_ * FOUT * FIN);        // 8 KB

    hipMemsetAsync(d_out, 0, (size_t)out_size * sizeof(float), stream);
    k_bias<<<dim3(N_ * N_ / 1024), 256, 0, stream>>>(adj, bias, biasm);
    k_wt<<<dim3(H_), 256, 0, stream>>>(W, WT);
    k_wa<<<dim3(H_), 256, 0, stream>>>(W, a, wa);
    k_s12<<<dim3(B_ * N_ / 16), 256, 0, stream>>>(hsrc, wa, s1, s2T);
    k_ht<<<dim3(B_ * N_ / 64), 256, 0, stream>>>(hsrc, hbT);
    k_pv2<<<dim3(2048), 256, 0, stream>>>(hbT, s1, s2T, biasm, WT, out);
}

// Round 16
// 76.294 us; speedup vs baseline: 1.8359x; 1.1664x over previous
//
#include <hip/hip_runtime.h>
#include <hip/hip_bf16.h>
#include <math.h>

#define B_   8
#define N_   1024
#define FIN  128
#define FOUT 128
#define H_   8
#define NEG  0.2f
#define LOG2E 1.4426950408889634f

typedef __attribute__((ext_vector_type(4))) float f32x4;
typedef __attribute__((ext_vector_type(8))) short s16x8;

static __device__ __forceinline__ unsigned short f2bf(float f) {
    unsigned int u = __float_as_uint(f);
    unsigned int r = (u + 0x7fffu + ((u >> 16) & 1u)) >> 16;   // RNE (software)
    return (unsigned short)r;
}

static __device__ __forceinline__ unsigned short f2bf_hw(float f) {
    union { __hip_bfloat16 b; unsigned short u; } cv;
    cv.b = __float2bfloat16(f);
    return cv.u;
}

// ---------------- K_PREP: fused {bias-mask | W->WT | wa | h->hbT | zero-out} ---------
// grid 1680, branch by block range (all branches block-uniform)
__global__ __launch_bounds__(256) void k_prep(const int* __restrict__ adj,
                                              const float* __restrict__ bias,
                                              const float* __restrict__ W,
                                              const float* __restrict__ a,
                                              const float* __restrict__ hsrc,
                                              float* __restrict__ biasm,
                                              unsigned short* __restrict__ WT,
                                              float* __restrict__ wa,
                                              unsigned short* __restrict__ hbT,
                                              float* __restrict__ outz) {
    __shared__ float tf[64][132];
    const int blk = blockIdx.x;
    const int t   = threadIdx.x;

    if (blk < 1024) {
        // ---- biasm[i][j] = adj ? bias*log2e : -inf (f32), 4 elems/thread
        const int base = (blk * 256 + t) * 4;
        int4   av = *(const int4*)&adj[base];
        float4 bv = *(const float4*)&bias[base];
        const float NINF = -__builtin_inff();
        float4 r;
        r.x = av.x ? bv.x * LOG2E : NINF;
        r.y = av.y ? bv.y * LOG2E : NINF;
        r.z = av.z ? bv.z * LOG2E : NINF;
        r.w = av.w ? bv.w * LOG2E : NINF;
        *(float4*)&biasm[base] = r;
    } else if (blk < 1032) {
        // ---- WT[h][fout][fin] bf16
        const int hd  = blk - 1024;
        const int fo  = t >> 1;
        const int fi0 = (t & 1) * 64;
        const float* src = W + (size_t)hd * FIN * FOUT;
        unsigned short* dst = WT + ((size_t)hd * FOUT + fo) * FIN + fi0;
#pragma unroll
        for (int c = 0; c < 8; ++c) {
            s16x8 v;
#pragma unroll
            for (int u = 0; u < 8; ++u)
                v[u] = (short)f2bf(src[(size_t)(fi0 + c * 8 + u) * FOUT + fo]);
            *(s16x8*)(dst + c * 8) = v;
        }
    } else if (blk < 1040) {
        // ---- wa[h][which][k] = log2e * W[h][k][:] . a[h][which][:]
        const int hd = blk - 1032;
        const int which = t >> 7, k = t & 127;
        const float* wrow = W + ((size_t)hd * FIN + k) * FOUT;
        const float* av   = a + (size_t)hd * 2 * FOUT + which * FOUT;
        float s = 0.f;
#pragma unroll 8
        for (int f = 0; f < FOUT; f += 4) {
            float4 wv = *(const float4*)&wrow[f];
            float4 a4 = *(const float4*)&av[f];
            s += wv.x * a4.x + wv.y * a4.y + wv.z * a4.z + wv.w * a4.w;
        }
        wa[((size_t)hd * 2 + which) * FIN + k] = s * LOG2E;
    } else if (blk < 1168) {
        // ---- hbT[b][k][n] bf16 transpose
        const int bn0 = (blk - 1040) * 64;
        const int b   = bn0 >> 10;
        const int n0  = bn0 & 1023;
        {
            const int r = t >> 2, k0 = (t & 3) * 32;
            const float* src = hsrc + (size_t)(bn0 + r) * FIN + k0;
#pragma unroll
            for (int c = 0; c < 8; ++c)
                *(float4*)&tf[r][k0 + c * 4] = *(const float4*)&src[c * 4];
        }
        __syncthreads();
        {
            const int k   = t >> 1;
            const int seg = (t & 1) * 32;
            unsigned short* dst = hbT + ((size_t)b * FIN + k) * N_ + n0 + seg;
#pragma unroll
            for (int c = 0; c < 4; ++c) {
                s16x8 v;
#pragma unroll
                for (int u = 0; u < 8; ++u)
                    v[u] = (short)f2bf_hw(tf[seg + c * 8 + u][k]);
                *(s16x8*)(dst + c * 8) = v;
            }
        }
    } else {
        // ---- zero out[] : 512 blocks x 2048 floats
        const int base = ((blk - 1168) * 256 + t) * 8;
        const float4 z4 = make_float4(0.f, 0.f, 0.f, 0.f);
        *(float4*)&outz[base]     = z4;
        *(float4*)&outz[base + 4] = z4;
    }
}

// ---------------- K0d: s1[bn][h], s2T[h][bn] = h . wa  (exact f32, pre-scaled) -------
__global__ __launch_bounds__(256) void k_s12(const float* __restrict__ hsrc,
                                             const float* __restrict__ wa,
                                             float* __restrict__ s1,
                                             float* __restrict__ s2T) {
    __shared__ float hrow[16][132];
    __shared__ float wal[16][132];
    const int t   = threadIdx.x;
    const int bn0 = blockIdx.x * 16;
    {
        const int r = t >> 4, c = (t & 15) * 8;
        *(float4*)&wal[r][c]     = *(const float4*)&wa[r * FIN + c];
        *(float4*)&wal[r][c + 4] = *(const float4*)&wa[r * FIN + c + 4];
        *(float4*)&hrow[r][c]     = *(const float4*)&hsrc[(size_t)(bn0 + r) * FIN + c];
        *(float4*)&hrow[r][c + 4] = *(const float4*)&hsrc[(size_t)(bn0 + r) * FIN + c + 4];
    }
    __syncthreads();
    const int r = t >> 4, sub = t & 15;
    const int hd = sub >> 1, which = sub & 1;
    float s = 0.f;
#pragma unroll 8
    for (int k = 0; k < FIN; k += 4) {
        float4 hv = *(const float4*)&hrow[r][k];
        float4 wv = *(const float4*)&wal[sub][k];
        s += hv.x * wv.x + hv.y * wv.y + hv.z * wv.z + hv.w * wv.w;
    }
    const int bn = bn0 + r;
    if (which == 0) s1[(size_t)bn * 8 + hd] = s;
    else            s2T[(size_t)hd * (B_ * N_) + bn] = s;
}

// ---------------- K2: fused P-gen + MFMA (P.h) + fused G@W epilogue ------------------
// (byte-identical to R15's 60.7us version)
__global__ __launch_bounds__(256, 5) void k_pv2(const unsigned short* __restrict__ hbT,
                                                const float* __restrict__ s1,
                                                const float* __restrict__ s2T,
                                                const float* __restrict__ biasm,
                                                const unsigned short* __restrict__ WT,
                                                float* __restrict__ out) {
    __shared__ __align__(16) unsigned short P[32][72];     // 4.5 KB
    __shared__ __align__(16) unsigned short Bl[128 * 64];  // 16 KB, XOR-swizzled chunks
    __shared__ __align__(16) unsigned short Gl[32][136];   // 8.5 KB, padded
    __shared__ float Zl[32];
    const int t    = threadIdx.x;
    const int lane = t & 63;
    const int wave = t >> 6;
    const int wg  = blockIdx.x;
    const int swz = ((wg & 7) << 8) | (wg >> 3);
    const int i0  = (swz & 31) * 32;
    const int hd  = (swz >> 5) & 7;
    const int b   = swz >> 8;

    const int prow = t >> 3;          // 0..31
    const int pj0  = (t & 7) * 8;     // 0..56
    const int gi   = (b << 10) + i0 + prow;
    const float s1v = s1[(size_t)gi * 8 + hd];
    const float* bm_row = biasm + (size_t)(i0 + prow) * N_;
    const float* s2p    = s2T + (size_t)hd * (B_ * N_) + (b << 10);

    const unsigned short* hpS = hbT + (size_t)b * FIN * N_;
    const int brow = t >> 3;
    const int bc   = t & 7;

    const int wr = (wave & 1) * 16;
    const int wc = (wave >> 1) * 64;
    const int arow = wr + (lane & 15);
    const int koff = (lane >> 4) * 8;

    f32x4 acc[4];
#pragma unroll
    for (int j = 0; j < 4; ++j) acc[j] = (f32x4){0.f, 0.f, 0.f, 0.f};
    float z_acc = 0.f;

    float4 bmv[2], sv[2];
    s16x8 Breg[4];

    auto load_it = [&](int j0) {
#pragma unroll
        for (int q = 0; q < 2; ++q) {
            bmv[q] = *(const float4*)&bm_row[j0 + pj0 + q * 4];
            sv[q]  = *(const float4*)&s2p[j0 + pj0 + q * 4];
        }
    };
    auto bload = [&](int j0) {
#pragma unroll
        for (int q = 0; q < 4; ++q)
            Breg[q] = *(const s16x8*)&hpS[(size_t)(brow + q * 32) * N_ + j0 + bc * 8];
    };
    auto phaseA = [&]() {
#pragma unroll
        for (int q = 0; q < 4; ++q) {
            int row = brow + q * 32;
            *(s16x8*)&Bl[row * 64 + ((bc ^ (row & 7)) * 8)] = Breg[q];
        }
        s16x8 pv;
#pragma unroll
        for (int q = 0; q < 2; ++q) {
            float x0 = s1v + sv[q].x; x0 = fmaxf(x0, NEG * x0) + bmv[q].x;
            float x1 = s1v + sv[q].y; x1 = fmaxf(x1, NEG * x1) + bmv[q].y;
            float x2 = s1v + sv[q].z; x2 = fmaxf(x2, NEG * x2) + bmv[q].z;
            float x3 = s1v + sv[q].w; x3 = fmaxf(x3, NEG * x3) + bmv[q].w;
            float p0 = exp2f(x0);   // exp2(-inf) = 0 handles the adj mask
            float p1 = exp2f(x1);
            float p2 = exp2f(x2);
            float p3 = exp2f(x3);
            z_acc += (p0 + p1) + (p2 + p3);
            pv[q * 4 + 0] = (short)f2bf_hw(p0);
            pv[q * 4 + 1] = (short)f2bf_hw(p1);
            pv[q * 4 + 2] = (short)f2bf_hw(p2);
            pv[q * 4 + 3] = (short)f2bf_hw(p3);
        }
        *(s16x8*)&P[prow][pj0] = pv;
    };

    // ---- main loop: G_tile = P . h
    bload(0);
    load_it(0);
    for (int it = 0; it < 16; ++it) {
        const int j0 = it * 64;
        phaseA();
        __syncthreads();
        if (it < 15) { bload(j0 + 64); load_it(j0 + 64); }
#pragma unroll
        for (int kw = 0; kw < 2; ++kw) {
            s16x8 a0 = *(const s16x8*)&P[arow][kw * 32 + koff];
#pragma unroll
            for (int fc = 0; fc < 4; ++fc) {
                const int r = wc + fc * 16 + (lane & 15);
                const int chunk = (lane >> 4) + kw * 4;
                s16x8 bf = *(const s16x8*)&Bl[r * 64 + ((chunk ^ (r & 7)) * 8)];
                acc[fc] = __builtin_amdgcn_mfma_f32_16x16x32_bf16(a0, bf, acc[fc], 0, 0, 0);
            }
        }
        __syncthreads();
    }

    // ---- Z: reduce 8 lanes per row
    float z = z_acc;
    z += __shfl_xor(z, 1); z += __shfl_xor(z, 2); z += __shfl_xor(z, 4);
    if ((t & 7) == 0) Zl[prow] = 0.125f / z;   // folds softmax norm + head-mean

    const unsigned short* Wsrc = WT + (size_t)hd * FOUT * FIN;
    s16x8 Wreg[4];
#pragma unroll
    for (int q = 0; q < 4; ++q)
        Wreg[q] = *(const s16x8*)&Wsrc[(size_t)(brow + q * 32) * FIN + bc * 8];
    __syncthreads();   // Zl visible; Bl free

#pragma unroll
    for (int r = 0; r < 4; ++r) {
        const int il = wr + (lane >> 4) * 4 + r;
        const float sc = Zl[il];
#pragma unroll
        for (int fc = 0; fc < 4; ++fc)
            Gl[il][wc + fc * 16 + (lane & 15)] = f2bf_hw(acc[fc][r] * sc);
    }
#pragma unroll
    for (int q = 0; q < 4; ++q) {
        int row = brow + q * 32;
        *(s16x8*)&Bl[row * 64 + ((bc ^ (row & 7)) * 8)] = Wreg[q];
    }
#pragma unroll
    for (int q = 0; q < 4; ++q)
        Wreg[q] = *(const s16x8*)&Wsrc[(size_t)(brow + q * 32) * FIN + 64 + bc * 8];
    __syncthreads();   // Gl + W-half0 visible

    const int wr2 = (wave & 1) * 16;
    const int wc2 = (wave >> 1) * 64;
    f32x4 acc2[4];
#pragma unroll
    for (int j = 0; j < 4; ++j) acc2[j] = (f32x4){0.f, 0.f, 0.f, 0.f};

#pragma unroll
    for (int kw = 0; kw < 2; ++kw) {                 // k 0..63
        s16x8 a0 = *(const s16x8*)&Gl[wr2 + (lane & 15)][kw * 32 + koff];
#pragma unroll
        for (int fc = 0; fc < 4; ++fc) {
            const int rb = wc2 + fc * 16 + (lane & 15);
            const int chunk = (lane >> 4) + kw * 4;
            s16x8 bf = *(const s16x8*)&Bl[rb * 64 + ((chunk ^ (rb & 7)) * 8)];
            acc2[fc] = __builtin_amdgcn_mfma_f32_16x16x32_bf16(a0, bf, acc2[fc], 0, 0, 0);
        }
    }
    __syncthreads();   // done reading W-half0
#pragma unroll
    for (int q = 0; q < 4; ++q) {                    // W half-1 into Bl
        int row = brow + q * 32;
        *(s16x8*)&Bl[row * 64 + ((bc ^ (row & 7)) * 8)] = Wreg[q];
    }
    __syncthreads();
#pragma unroll
    for (int kw = 0; kw < 2; ++kw) {                 // k 64..127
        s16x8 a0 = *(const s16x8*)&Gl[wr2 + (lane & 15)][64 + kw * 32 + koff];
#pragma unroll
        for (int fc = 0; fc < 4; ++fc) {
            const int rb = wc2 + fc * 16 + (lane & 15);
            const int chunk = (lane >> 4) + kw * 4;
            s16x8 bf = *(const s16x8*)&Bl[rb * 64 + ((chunk ^ (rb & 7)) * 8)];
            acc2[fc] = __builtin_amdgcn_mfma_f32_16x16x32_bf16(a0, bf, acc2[fc], 0, 0, 0);
        }
    }

#pragma unroll
    for (int r = 0; r < 4; ++r) {
        const int il = wr2 + (lane >> 4) * 4 + r;
        float* op = out + ((size_t)((b << 10) + i0 + il)) * FOUT + wc2 + (lane & 15);
#pragma unroll
        for (int fc = 0; fc < 4; ++fc)
            unsafeAtomicAdd(op + fc * 16, acc2[fc][r]);
    }
}

extern "C" void kernel_launch(void* const* d_in, const int* in_sizes, int n_in,
                              void* d_out, int out_size, void* d_ws, size_t ws_size,
                              hipStream_t stream) {
    const float* hsrc = (const float*)d_in[0];
    const int*   adj  = (const int*)d_in[1];
    const float* bias = (const float*)d_in[2];
    const float* W    = (const float*)d_in[3];
    const float* a    = (const float*)d_in[4];
    float* out = (float*)d_out;

    char* ws = (char*)d_ws;
    unsigned short* hbT = (unsigned short*)ws;                 // 2 MB (bf16 h^T per batch)
    float* s1    = (float*)(ws + 2097152);                     // 256 KB
    float* s2T   = s1 + 65536;                                 // 256 KB
    float* biasm = s2T + 65536;                                // 4 MB (f32, log2e-scaled)
    unsigned short* WT = (unsigned short*)(biasm + N_ * N_);   // 256 KB
    float* wa = (float*)(WT + (size_t)H_ * FOUT * FIN);        // 8 KB

    k_prep<<<dim3(1680), 256, 0, stream>>>(adj, bias, W, a, hsrc,
                                           biasm, WT, wa, hbT, out);
    k_s12<<<dim3(B_ * N_ / 16), 256, 0, stream>>>(hsrc, wa, s1, s2T);
    k_pv2<<<dim3(2048), 256, 0, stream>>>(hbT, s1, s2T, biasm, WT, out);
}

// Round 17
// 63.338 us; speedup vs baseline: 2.2114x; 1.2046x over previous
//
#include <hip/hip_runtime.h>
#include <hip/hip_bf16.h>
#include <math.h>

#define B_   8
#define N_   1024
#define FIN  128
#define FOUT 128
#define H_   8
#define NEG  0.2f
#define LOG2E 1.4426950408889634f

typedef __attribute__((ext_vector_type(4))) float f32x4;
typedef __attribute__((ext_vector_type(8))) short s16x8;

static __device__ __forceinline__ unsigned short f2bf(float f) {
    unsigned int u = __float_as_uint(f);
    unsigned int r = (u + 0x7fffu + ((u >> 16) & 1u)) >> 16;   // RNE (software)
    return (unsigned short)r;
}

static __device__ __forceinline__ unsigned short f2bf_hw(float f) {
    union { __hip_bfloat16 b; unsigned short u; } cv;
    cv.b = __float2bfloat16(f);
    return cv.u;
}

// ---------------- K_PREP: fused {bias-mask | W->WT | wa | h->hbT} --------------------
// grid 1168, branch by block range (all branches block-uniform)
__global__ __launch_bounds__(256) void k_prep(const int* __restrict__ adj,
                                              const float* __restrict__ bias,
                                              const float* __restrict__ W,
                                              const float* __restrict__ a,
                                              const float* __restrict__ hsrc,
                                              float* __restrict__ biasm,
                                              unsigned short* __restrict__ WT,
                                              float* __restrict__ wa,
                                              unsigned short* __restrict__ hbT) {
    __shared__ float tf[64][132];
    const int blk = blockIdx.x;
    const int t   = threadIdx.x;

    if (blk < 1024) {
        // ---- biasm[i][j] = adj ? bias*log2e : -inf (f32), 4 elems/thread
        const int base = (blk * 256 + t) * 4;
        int4   av = *(const int4*)&adj[base];
        float4 bv = *(const float4*)&bias[base];
        const float NINF = -__builtin_inff();
        float4 r;
        r.x = av.x ? bv.x * LOG2E : NINF;
        r.y = av.y ? bv.y * LOG2E : NINF;
        r.z = av.z ? bv.z * LOG2E : NINF;
        r.w = av.w ? bv.w * LOG2E : NINF;
        *(float4*)&biasm[base] = r;
    } else if (blk < 1032) {
        // ---- WT[h][fout][fin] bf16
        const int hd  = blk - 1024;
        const int fo  = t >> 1;
        const int fi0 = (t & 1) * 64;
        const float* src = W + (size_t)hd * FIN * FOUT;
        unsigned short* dst = WT + ((size_t)hd * FOUT + fo) * FIN + fi0;
#pragma unroll
        for (int c = 0; c < 8; ++c) {
            s16x8 v;
#pragma unroll
            for (int u = 0; u < 8; ++u)
                v[u] = (short)f2bf(src[(size_t)(fi0 + c * 8 + u) * FOUT + fo]);
            *(s16x8*)(dst + c * 8) = v;
        }
    } else if (blk < 1040) {
        // ---- wa[h][which][k] = log2e * W[h][k][:] . a[h][which][:]
        const int hd = blk - 1032;
        const int which = t >> 7, k = t & 127;
        const float* wrow = W + ((size_t)hd * FIN + k) * FOUT;
        const float* av   = a + (size_t)hd * 2 * FOUT + which * FOUT;
        float s = 0.f;
#pragma unroll 8
        for (int f = 0; f < FOUT; f += 4) {
            float4 wv = *(const float4*)&wrow[f];
            float4 a4 = *(const float4*)&av[f];
            s += wv.x * a4.x + wv.y * a4.y + wv.z * a4.z + wv.w * a4.w;
        }
        wa[((size_t)hd * 2 + which) * FIN + k] = s * LOG2E;
    } else {
        // ---- hbT[b][k][n] bf16 transpose
        const int bn0 = (blk - 1040) * 64;
        const int b   = bn0 >> 10;
        const int n0  = bn0 & 1023;
        {
            const int r = t >> 2, k0 = (t & 3) * 32;
            const float* src = hsrc + (size_t)(bn0 + r) * FIN + k0;
#pragma unroll
            for (int c = 0; c < 8; ++c)
                *(float4*)&tf[r][k0 + c * 4] = *(const float4*)&src[c * 4];
        }
        __syncthreads();
        {
            const int k   = t >> 1;
            const int seg = (t & 1) * 32;
            unsigned short* dst = hbT + ((size_t)b * FIN + k) * N_ + n0 + seg;
#pragma unroll
            for (int c = 0; c < 4; ++c) {
                s16x8 v;
#pragma unroll
                for (int u = 0; u < 8; ++u)
                    v[u] = (short)f2bf_hw(tf[seg + c * 8 + u][k]);
                *(s16x8*)(dst + c * 8) = v;
            }
        }
    }
}

// ---------------- K0d: s1/s2 (blocks <512) + zero-out (blocks >=512) -----------------
__global__ __launch_bounds__(256) void k_s12(const float* __restrict__ hsrc,
                                             const float* __restrict__ wa,
                                             float* __restrict__ s1,
                                             float* __restrict__ s2T,
                                             float* __restrict__ outz) {
    __shared__ float hrow[16][132];
    __shared__ float wal[16][132];
    const int t   = threadIdx.x;
    const int blk = blockIdx.x;
    if (blk >= 512) {
        const int base = ((blk - 512) * 256 + t) * 8;
        const float4 z4 = make_float4(0.f, 0.f, 0.f, 0.f);
        *(float4*)&outz[base]     = z4;
        *(float4*)&outz[base + 4] = z4;
        return;
    }
    const int bn0 = blk * 16;
    {
        const int r = t >> 4, c = (t & 15) * 8;
        *(float4*)&wal[r][c]     = *(const float4*)&wa[r * FIN + c];
        *(float4*)&wal[r][c + 4] = *(const float4*)&wa[r * FIN + c + 4];
        *(float4*)&hrow[r][c]     = *(const float4*)&hsrc[(size_t)(bn0 + r) * FIN + c];
        *(float4*)&hrow[r][c + 4] = *(const float4*)&hsrc[(size_t)(bn0 + r) * FIN + c + 4];
    }
    __syncthreads();
    const int r = t >> 4, sub = t & 15;
    const int hd = sub >> 1, which = sub & 1;
    float s = 0.f;
#pragma unroll 8
    for (int k = 0; k < FIN; k += 4) {
        float4 hv = *(const float4*)&hrow[r][k];
        float4 wv = *(const float4*)&wal[sub][k];
        s += hv.x * wv.x + hv.y * wv.y + hv.z * wv.z + hv.w * wv.w;
    }
    const int bn = bn0 + r;
    if (which == 0) s1[(size_t)bn * 8 + hd] = s;
    else            s2T[(size_t)hd * (B_ * N_) + bn] = s;
}

// ---------------- K2: 2-heads-per-block fused P-gen + MFMA (P.h) + G@W epilogue ------
// grid 1024: XCD k <- batch k; per batch: 4 head-pairs x 32 i-tiles.
// B-tile (head-independent) staged ONCE per pair; bf ds_read feeds both heads' MFMAs.
__global__ __launch_bounds__(256, 4) void k_pv2(const unsigned short* __restrict__ hbT,
                                                const float* __restrict__ s1,
                                                const float* __restrict__ s2T,
                                                const float* __restrict__ biasm,
                                                const unsigned short* __restrict__ WT,
                                                float* __restrict__ out) {
    __shared__ __align__(16) unsigned short P[2][32 * 64];   // 8 KB, XOR-swizzled
    __shared__ __align__(16) unsigned short Bl[128 * 64];    // 16 KB, XOR-swizzled
    __shared__ __align__(16) unsigned short Gl[32][136];     // 8.5 KB, padded
    __shared__ float Zl[2][32];
    const int t    = threadIdx.x;
    const int lane = t & 63;
    const int wave = t >> 6;
    const int wg  = blockIdx.x;
    const int swz = ((wg & 7) << 7) | (wg >> 3);   // bijective (1024 % 8 == 0)
    const int i0  = (swz & 31) * 32;
    const int hp  = (swz >> 5) & 3;
    const int b   = swz >> 7;
    const int hd0 = hp * 2, hd1 = hd0 + 1;

    const int prow = t >> 3;          // 0..31
    const int pj0  = (t & 7) * 8;     // 0..56
    const int pchk = (t & 7) ^ (prow & 7);   // swizzled P chunk for store
    const int gi   = (b << 10) + i0 + prow;
    const float s1v0 = s1[(size_t)gi * 8 + hd0];
    const float s1v1 = s1[(size_t)gi * 8 + hd1];
    const float* bm_row = biasm + (size_t)(i0 + prow) * N_;
    const float* s2p0   = s2T + (size_t)hd0 * (B_ * N_) + (b << 10);
    const float* s2p1   = s2T + (size_t)hd1 * (B_ * N_) + (b << 10);

    const unsigned short* hpS = hbT + (size_t)b * FIN * N_;
    const int brow = t >> 3;
    const int bc   = t & 7;

    const int wr = (wave & 1) * 16;
    const int wc = (wave >> 1) * 64;
    const int arow = wr + (lane & 15);
    const int koff = (lane >> 4) * 8;

    f32x4 acc0[4], acc1[4];
#pragma unroll
    for (int j = 0; j < 4; ++j) {
        acc0[j] = (f32x4){0.f, 0.f, 0.f, 0.f};
        acc1[j] = (f32x4){0.f, 0.f, 0.f, 0.f};
    }
    float z0 = 0.f, z1 = 0.f;

    float4 bmv[2], sv0[2], sv1[2];
    s16x8 Breg[4];

    auto load_it = [&](int j0) {
#pragma unroll
        for (int q = 0; q < 2; ++q) {
            bmv[q] = *(const float4*)&bm_row[j0 + pj0 + q * 4];
            sv0[q] = *(const float4*)&s2p0[j0 + pj0 + q * 4];
            sv1[q] = *(const float4*)&s2p1[j0 + pj0 + q * 4];
        }
    };
    auto bload = [&](int j0) {
#pragma unroll
        for (int q = 0; q < 4; ++q)
            Breg[q] = *(const s16x8*)&hpS[(size_t)(brow + q * 32) * N_ + j0 + bc * 8];
    };
    auto pgen = [&](int h, float s1v, const float4* svh, float& zr) {
        s16x8 pv;
#pragma unroll
        for (int q = 0; q < 2; ++q) {
            float x0 = s1v + svh[q].x; x0 = fmaxf(x0, NEG * x0) + bmv[q].x;
            float x1 = s1v + svh[q].y; x1 = fmaxf(x1, NEG * x1) + bmv[q].y;
            float x2 = s1v + svh[q].z; x2 = fmaxf(x2, NEG * x2) + bmv[q].z;
            float x3 = s1v + svh[q].w; x3 = fmaxf(x3, NEG * x3) + bmv[q].w;
            float p0 = exp2f(x0);   // exp2(-inf) = 0 handles the adj mask
            float p1 = exp2f(x1);
            float p2 = exp2f(x2);
            float p3 = exp2f(x3);
            zr += (p0 + p1) + (p2 + p3);
            pv[q * 4 + 0] = (short)f2bf_hw(p0);
            pv[q * 4 + 1] = (short)f2bf_hw(p1);
            pv[q * 4 + 2] = (short)f2bf_hw(p2);
            pv[q * 4 + 3] = (short)f2bf_hw(p3);
        }
        *(s16x8*)&P[h][prow * 64 + pchk * 8] = pv;
    };
    auto phaseA = [&]() {
#pragma unroll
        for (int q = 0; q < 4; ++q) {
            int row = brow + q * 32;
            *(s16x8*)&Bl[row * 64 + ((bc ^ (row & 7)) * 8)] = Breg[q];
        }
        pgen(0, s1v0, sv0, z0);
        pgen(1, s1v1, sv1, z1);
    };

    // ---- main loop: G_tile(h) = P(h) . h  — one staged B serves both heads
    bload(0);
    load_it(0);
    for (int it = 0; it < 16; ++it) {
        const int j0 = it * 64;
        phaseA();
        __syncthreads();
        if (it < 15) { bload(j0 + 64); load_it(j0 + 64); }
#pragma unroll
        for (int kw = 0; kw < 2; ++kw) {
            const int chunk = kw * 4 + (lane >> 4);
            const int aoff = (chunk ^ (arow & 7)) * 8;
            s16x8 a00 = *(const s16x8*)&P[0][arow * 64 + aoff];
            s16x8 a01 = *(const s16x8*)&P[1][arow * 64 + aoff];
#pragma unroll
            for (int fc = 0; fc < 4; ++fc) {
                const int r = wc + fc * 16 + (lane & 15);
                s16x8 bf = *(const s16x8*)&Bl[r * 64 + ((chunk ^ (r & 7)) * 8)];
                acc0[fc] = __builtin_amdgcn_mfma_f32_16x16x32_bf16(a00, bf, acc0[fc], 0, 0, 0);
                acc1[fc] = __builtin_amdgcn_mfma_f32_16x16x32_bf16(a01, bf, acc1[fc], 0, 0, 0);
            }
        }
        __syncthreads();
    }

    // ---- Z for both heads (8 lanes per row)
    {
        float za = z0, zb = z1;
        za += __shfl_xor(za, 1); za += __shfl_xor(za, 2); za += __shfl_xor(za, 4);
        zb += __shfl_xor(zb, 1); zb += __shfl_xor(zb, 2); zb += __shfl_xor(zb, 4);
        if ((t & 7) == 0) {
            Zl[0][prow] = 0.125f / za;   // folds softmax norm + head-mean
            Zl[1][prow] = 0.125f / zb;
        }
    }

    const unsigned short* Wsrc0 = WT + (size_t)hd0 * FOUT * FIN;
    const unsigned short* Wsrc1 = WT + (size_t)hd1 * FOUT * FIN;
    s16x8 Wreg[4];
#pragma unroll
    for (int q = 0; q < 4; ++q)
        Wreg[q] = *(const s16x8*)&Wsrc0[(size_t)(brow + q * 32) * FIN + bc * 8];
    __syncthreads();   // Zl visible; P/Bl free

    const int wr2 = (wave & 1) * 16;
    const int wc2 = (wave >> 1) * 64;
    f32x4 acc2[4];
#pragma unroll
    for (int j = 0; j < 4; ++j) acc2[j] = (f32x4){0.f, 0.f, 0.f, 0.f};

    auto wstage = [&]() {
#pragma unroll
        for (int q = 0; q < 4; ++q) {
            int row = brow + q * 32;
            *(s16x8*)&Bl[row * 64 + ((bc ^ (row & 7)) * 8)] = Wreg[q];
        }
    };
    auto gw_mfma = [&](int half) {
#pragma unroll
        for (int kw = 0; kw < 2; ++kw) {
            const int chunk = kw * 4 + (lane >> 4);
            s16x8 a0 = *(const s16x8*)&Gl[wr2 + (lane & 15)][half * 64 + kw * 32 + koff];
#pragma unroll
            for (int fc = 0; fc < 4; ++fc) {
                const int rb = wc2 + fc * 16 + (lane & 15);
                s16x8 bf = *(const s16x8*)&Bl[rb * 64 + ((chunk ^ (rb & 7)) * 8)];
                acc2[fc] = __builtin_amdgcn_mfma_f32_16x16x32_bf16(a0, bf, acc2[fc], 0, 0, 0);
            }
        }
    };

    // ---- head 0: out += G0 @ W[hd0]
#pragma unroll
    for (int r = 0; r < 4; ++r) {
        const int il = wr + (lane >> 4) * 4 + r;
        const float sc = Zl[0][il];
#pragma unroll
        for (int fc = 0; fc < 4; ++fc)
            Gl[il][wc + fc * 16 + (lane & 15)] = f2bf_hw(acc0[fc][r] * sc);
    }
    wstage();
#pragma unroll
    for (int q = 0; q < 4; ++q)
        Wreg[q] = *(const s16x8*)&Wsrc0[(size_t)(brow + q * 32) * FIN + 64 + bc * 8];
    __syncthreads();   // Gl(h0) + W0-half0 visible
    gw_mfma(0);
    __syncthreads();
    wstage();
#pragma unroll
    for (int q = 0; q < 4; ++q)
        Wreg[q] = *(const s16x8*)&Wsrc1[(size_t)(brow + q * 32) * FIN + bc * 8];
    __syncthreads();   // W0-half1 visible
    gw_mfma(1);
    __syncthreads();   // all waves done reading Gl(h0) + Bl

    // ---- head 1: out += G1 @ W[hd1]
#pragma unroll
    for (int r = 0; r < 4; ++r) {
        const int il = wr + (lane >> 4) * 4 + r;
        const float sc = Zl[1][il];
#pragma unroll
        for (int fc = 0; fc < 4; ++fc)
            Gl[il][wc + fc * 16 + (lane & 15)] = f2bf_hw(acc1[fc][r] * sc);
    }
    wstage();
#pragma unroll
    for (int q = 0; q < 4; ++q)
        Wreg[q] = *(const s16x8*)&Wsrc1[(size_t)(brow + q * 32) * FIN + 64 + bc * 8];
    __syncthreads();   // Gl(h1) + W1-half0 visible
    gw_mfma(0);
    __syncthreads();
    wstage();
    __syncthreads();   // W1-half1 visible
    gw_mfma(1);

    // ---- accumulate 2-head partial into out
#pragma unroll
    for (int r = 0; r < 4; ++r) {
        const int il = wr2 + (lane >> 4) * 4 + r;
        float* op = out + ((size_t)((b << 10) + i0 + il)) * FOUT + wc2 + (lane & 15);
#pragma unroll
        for (int fc = 0; fc < 4; ++fc)
            unsafeAtomicAdd(op + fc * 16, acc2[fc][r]);
    }
}

extern "C" void kernel_launch(void* const* d_in, const int* in_sizes, int n_in,
                              void* d_out, int out_size, void* d_ws, size_t ws_size,
                              hipStream_t stream) {
    const float* hsrc = (const float*)d_in[0];
    const int*   adj  = (const int*)d_in[1];
    const float* bias = (const float*)d_in[2];
    const float* W    = (const float*)d_in[3];
    const float* a    = (const float*)d_in[4];
    float* out = (float*)d_out;

    char* ws = (char*)d_ws;
    unsigned short* hbT = (unsigned short*)ws;                 // 2 MB (bf16 h^T per batch)
    float* s1    = (float*)(ws + 2097152);                     // 256 KB
    float* s2T   = s1 + 65536;                                 // 256 KB
    float* biasm = s2T + 65536;                                // 4 MB (f32, log2e-scaled)
    unsigned short* WT = (unsigned short*)(biasm + N_ * N_);   // 256 KB
    float* wa = (float*)(WT + (size_t)H_ * FOUT * FIN);        // 8 KB

    k_prep<<<dim3(1168), 256, 0, stream>>>(adj, bias, W, a, hsrc,
                                           biasm, WT, wa, hbT);
    k_s12<<<dim3(1024), 256, 0, stream>>>(hsrc, wa, s1, s2T, out);
    k_pv2<<<dim3(1024), 256, 0, stream>>>(hbT, s1, s2T, biasm, WT, out);
}